// Round 1
// baseline (3164.587 us; speedup 1.0000x reference)
//
#include <hip/hip_runtime.h>
#include <hip/hip_bf16.h>

// Problem constants (B,D,H,W,C) = (2,32,56,56,96); WS=(2,7,7), SS=(1,3,3)
#define NTOK   200704      // B*D*H*W
#define NWIN   2048        // B * 1024 windows
#define NWB    1024        // windows per batch elem
#define NT     98          // tokens per window (2*7*7)
#define CCH    96
#define HEADS  3
#define HD     32
#define HID    384

__device__ __forceinline__ float bf2f(__hip_bfloat16 v) { return __bfloat162float(v); }

// ---------------- Kernel 1: LN1 + shift + window partition -> xw (bf16) ----
__global__ __launch_bounds__(256) void k1_ln_window(
    const float* __restrict__ x, const float* __restrict__ g,
    const float* __restrict__ bt, __hip_bfloat16* __restrict__ xw) {
  int token = blockIdx.x * 8 + (threadIdx.x >> 5);
  int lane = threadIdx.x & 31;
  if (token >= NTOK) return;
  int wb = token / NT;
  int n  = token - wb * NT;
  int b = wb >> 10;
  int rem = wb & 1023;
  int wd = rem >> 6, wh = (rem >> 3) & 7, ww = rem & 7;
  int id = n / 49, ih = (n / 7) % 7, iw = n % 7;
  int dd = wd * 2 + id + 1; if (dd >= 32) dd -= 32;
  int hh = wh * 7 + ih + 3; if (hh >= 56) hh -= 56;
  int w2 = ww * 7 + iw + 3; if (w2 >= 56) w2 -= 56;
  const float* src = x + ((((size_t)b * 32 + dd) * 56 + hh) * 56 + w2) * CCH;
  float v0 = src[lane], v1 = src[lane + 32], v2 = src[lane + 64];
  float s = v0 + v1 + v2, ss = v0 * v0 + v1 * v1 + v2 * v2;
  #pragma unroll
  for (int off = 16; off; off >>= 1) {
    s  += __shfl_xor(s,  off, 32);
    ss += __shfl_xor(ss, off, 32);
  }
  float m   = s * (1.f / 96.f);
  float inv = rsqrtf(ss * (1.f / 96.f) - m * m + 1e-5f);
  __hip_bfloat16* dst = xw + (size_t)token * CCH;
  dst[lane]      = __float2bfloat16((v0 - m) * inv * g[lane]      + bt[lane]);
  dst[lane + 32] = __float2bfloat16((v1 - m) * inv * g[lane + 32] + bt[lane + 32]);
  dst[lane + 64] = __float2bfloat16((v2 - m) * inv * g[lane + 64] + bt[lane + 64]);
}

// ---------------- Kernel 2: per (window, head) attention ------------------
// LDS: qs[98][34] bf16, kts[32][98] bf16, vs[98][34] bf16, Bb = union(xw[98][97] f32, S[98][98] f32)
__global__ __launch_bounds__(256) void k2_attn(
    const __hip_bfloat16* __restrict__ xw,
    const float* __restrict__ qkv_w, const float* __restrict__ qkv_b,
    const float* __restrict__ mask, __hip_bfloat16* __restrict__ obuf) {
  __shared__ __hip_bfloat16 qs[NT * 34];
  __shared__ __hip_bfloat16 kts[HD * NT];
  __shared__ __hip_bfloat16 vs[NT * 34];
  __shared__ float Bb[NT * NT];   // 9604 floats; first phase holds xw as [98][97]
  int wb = blockIdx.x, h = blockIdx.y, tid = threadIdx.x;

  const __hip_bfloat16* xp = xw + (size_t)wb * (NT * CCH);
  for (int idx = tid; idx < NT * CCH; idx += 256) {
    int n = idx / CCH, c = idx - n * CCH;
    Bb[n * 97 + c] = bf2f(xp[idx]);
  }
  __syncthreads();

  // qkv for this head: 3 (q/k/v) x 8 d-quads x 98 tokens
  for (int o = tid; o < 3 * 8 * NT; o += 256) {
    int which = o / 784;
    int r = o - which * 784;
    int d4 = r / NT;
    int n = r - d4 * NT;
    int row0 = which * CCH + h * HD + d4 * 4;
    const float* w0 = qkv_w + (size_t)row0 * CCH;
    float a0 = qkv_b[row0], a1 = qkv_b[row0 + 1], a2 = qkv_b[row0 + 2], a3 = qkv_b[row0 + 3];
    const float* xr = &Bb[n * 97];
    #pragma unroll 4
    for (int c = 0; c < CCH; ++c) {
      float xv = xr[c];
      a0 += xv * w0[c];
      a1 += xv * w0[CCH + c];
      a2 += xv * w0[2 * CCH + c];
      a3 += xv * w0[3 * CCH + c];
    }
    int d = d4 * 4;
    if (which == 0) {
      const float sc = 0.17677669529663689f;  // 32^-0.5
      qs[n * 34 + d]     = __float2bfloat16(a0 * sc);
      qs[n * 34 + d + 1] = __float2bfloat16(a1 * sc);
      qs[n * 34 + d + 2] = __float2bfloat16(a2 * sc);
      qs[n * 34 + d + 3] = __float2bfloat16(a3 * sc);
    } else if (which == 1) {
      kts[(d)     * NT + n] = __float2bfloat16(a0);
      kts[(d + 1) * NT + n] = __float2bfloat16(a1);
      kts[(d + 2) * NT + n] = __float2bfloat16(a2);
      kts[(d + 3) * NT + n] = __float2bfloat16(a3);
    } else {
      vs[n * 34 + d]     = __float2bfloat16(a0);
      vs[n * 34 + d + 1] = __float2bfloat16(a1);
      vs[n * 34 + d + 2] = __float2bfloat16(a2);
      vs[n * 34 + d + 3] = __float2bfloat16(a3);
    }
  }
  __syncthreads();

  // S = q k^T + mask  (overwrites xw region)
  const float* mrow = mask + (size_t)(wb & 1023) * (NT * NT);
  for (int o = tid; o < 49 * NT; o += 256) {
    int i2 = o / NT, j = o - i2 * NT;
    int i0 = i2 * 2;
    float a0 = 0.f, a1 = 0.f;
    #pragma unroll
    for (int d = 0; d < HD; ++d) {
      float kv = bf2f(kts[d * NT + j]);
      a0 += bf2f(qs[i0 * 34 + d]) * kv;
      a1 += bf2f(qs[(i0 + 1) * 34 + d]) * kv;
    }
    Bb[i0 * NT + j]       = a0 + mrow[i0 * NT + j];
    Bb[(i0 + 1) * NT + j] = a1 + mrow[(i0 + 1) * NT + j];
  }
  __syncthreads();

  // softmax per row
  if (tid < NT) {
    float* row = &Bb[tid * NT];
    float mx = -1e30f;
    for (int j = 0; j < NT; ++j) mx = fmaxf(mx, row[j]);
    float sum = 0.f;
    for (int j = 0; j < NT; ++j) { float e = __expf(row[j] - mx); row[j] = e; sum += e; }
    float inv = 1.f / sum;
    for (int j = 0; j < NT; ++j) row[j] *= inv;
  }
  __syncthreads();

  // O = P V -> obuf (bf16), layout (window, n, h*32+d)
  __hip_bfloat16* op = obuf + (size_t)wb * (NT * CCH) + h * HD;
  for (int o = tid; o < 49 * HD; o += 256) {
    int i2 = o / HD, d = o - i2 * HD;
    int i0 = 2 * i2;
    float a0 = 0.f, a1 = 0.f;
    for (int j = 0; j < NT; ++j) {
      float vv = bf2f(vs[j * 34 + d]);
      a0 += Bb[i0 * NT + j] * vv;
      a1 += Bb[(i0 + 1) * NT + j] * vv;
    }
    op[(size_t)i0 * CCH + d]       = __float2bfloat16(a0);
    op[(size_t)(i0 + 1) * CCH + d] = __float2bfloat16(a1);
  }
}

// ---------------- Kernel 3: proj + window-reverse + unshift + residual ----
__global__ __launch_bounds__(256) void k3_proj(
    const __hip_bfloat16* __restrict__ obuf, const float* __restrict__ x,
    const float* __restrict__ pw, const float* __restrict__ pb,
    float* __restrict__ out) {
  __shared__ __hip_bfloat16 os[NT * 98];  // stride 98
  __shared__ float outs[NT * 97];
  int wb = blockIdx.x, tid = threadIdx.x;
  const __hip_bfloat16* src = obuf + (size_t)wb * (NT * CCH);
  for (int idx = tid; idx < NT * CCH; idx += 256) {
    int n = idx / CCH, c = idx - n * CCH;
    os[n * 98 + c] = src[idx];
  }
  __syncthreads();
  for (int o = tid; o < 48 * NT; o += 256) {
    int c2 = o / NT, n = o - c2 * NT;
    int c0 = c2 * 2;
    const float* w0 = pw + (size_t)c0 * CCH;
    float a0 = pb[c0], a1 = pb[c0 + 1];
    const __hip_bfloat16* orow = &os[n * 98];
    #pragma unroll 4
    for (int cc = 0; cc < CCH; ++cc) {
      float ov = bf2f(orow[cc]);
      a0 += ov * w0[cc];
      a1 += ov * w0[CCH + cc];
    }
    outs[n * 97 + c0]     = a0;
    outs[n * 97 + c0 + 1] = a1;
  }
  __syncthreads();
  int b = wb >> 10, rem = wb & 1023;
  int wd = rem >> 6, wh = (rem >> 3) & 7, ww = rem & 7;
  for (int o = tid; o < NT * CCH; o += 256) {
    int n = o / CCH, c = o - n * CCH;
    int id = n / 49, ih = (n / 7) % 7, iw = n % 7;
    int dd = wd * 2 + id + 1; if (dd >= 32) dd -= 32;
    int hh = wh * 7 + ih + 3; if (hh >= 56) hh -= 56;
    int w2 = ww * 7 + iw + 3; if (w2 >= 56) w2 -= 56;
    size_t gi = ((((size_t)b * 32 + dd) * 56 + hh) * 56 + w2) * CCH + c;
    out[gi] = x[gi] + outs[n * 97 + c];
  }
}

// ---------------- Kernel 4: LN2 + fc1 + GELU + fc2 + residual (in-place) --
__global__ __launch_bounds__(256) void k4_mlp(
    float* __restrict__ io, const float* __restrict__ g, const float* __restrict__ bt,
    const float* __restrict__ w1, const float* __restrict__ b1,
    const float* __restrict__ w2, const float* __restrict__ b2) {
  __shared__ float hs[32 * 97];     // LN'd tokens, later out staging
  __shared__ float hid[32 * 389];   // gelu(fc1)
  int tid = threadIdx.x;
  size_t base = (size_t)blockIdx.x * 32 * CCH;
  int hw = tid >> 5, lane = tid & 31;
  for (int t = hw; t < 32; t += 8) {
    const float* src = io + base + (size_t)t * CCH;
    float v0 = src[lane], v1 = src[lane + 32], v2 = src[lane + 64];
    float s = v0 + v1 + v2, ss = v0 * v0 + v1 * v1 + v2 * v2;
    #pragma unroll
    for (int off = 16; off; off >>= 1) {
      s  += __shfl_xor(s,  off, 32);
      ss += __shfl_xor(ss, off, 32);
    }
    float m   = s * (1.f / 96.f);
    float inv = rsqrtf(ss * (1.f / 96.f) - m * m + 1e-5f);
    hs[t * 97 + lane]      = (v0 - m) * inv * g[lane]      + bt[lane];
    hs[t * 97 + lane + 32] = (v1 - m) * inv * g[lane + 32] + bt[lane + 32];
    hs[t * 97 + lane + 64] = (v2 - m) * inv * g[lane + 64] + bt[lane + 64];
  }
  __syncthreads();
  // fc1 + gelu: 48 u8-groups x 32 tokens (t fastest -> uniform weight rows)
  for (int o = tid; o < 32 * 48; o += 256) {
    int u8 = o >> 5, t = o & 31;
    int u0 = u8 * 8;
    float acc[8];
    #pragma unroll
    for (int k = 0; k < 8; ++k) acc[k] = b1[u0 + k];
    const float* hr = &hs[t * 97];
    for (int c = 0; c < CCH; c += 4) {
      float h0 = hr[c], h1 = hr[c + 1], h2 = hr[c + 2], h3 = hr[c + 3];
      #pragma unroll
      for (int k = 0; k < 8; ++k) {
        float4 wv = *(const float4*)(w1 + (size_t)(u0 + k) * CCH + c);
        acc[k] += h0 * wv.x + h1 * wv.y + h2 * wv.z + h3 * wv.w;
      }
    }
    #pragma unroll
    for (int k = 0; k < 8; ++k) {
      float hv = acc[k];
      hid[t * 389 + u0 + k] = 0.5f * hv * (1.f + erff(hv * 0.70710678118654752f));
    }
  }
  __syncthreads();
  // fc2 into hs staging: 24 c4-groups x 32 tokens
  for (int o = tid; o < 32 * 24; o += 256) {
    int c4 = o >> 5, t = o & 31;
    int c0 = c4 * 4;
    float a0 = b2[c0], a1 = b2[c0 + 1], a2 = b2[c0 + 2], a3 = b2[c0 + 3];
    const float* hr = &hid[t * 389];
    for (int u = 0; u < HID; u += 2) {
      float hv0 = hr[u], hv1 = hr[u + 1];
      float2 w0 = *(const float2*)(w2 + (size_t)(c0)     * HID + u);
      float2 w1v = *(const float2*)(w2 + (size_t)(c0 + 1) * HID + u);
      float2 w2v = *(const float2*)(w2 + (size_t)(c0 + 2) * HID + u);
      float2 w3v = *(const float2*)(w2 + (size_t)(c0 + 3) * HID + u);
      a0 += hv0 * w0.x + hv1 * w0.y;
      a1 += hv0 * w1v.x + hv1 * w1v.y;
      a2 += hv0 * w2v.x + hv1 * w2v.y;
      a3 += hv0 * w3v.x + hv1 * w3v.y;
    }
    hs[t * 97 + c0] = a0; hs[t * 97 + c0 + 1] = a1;
    hs[t * 97 + c0 + 2] = a2; hs[t * 97 + c0 + 3] = a3;
  }
  __syncthreads();
  for (int o = tid; o < 32 * CCH; o += 256) {
    int t = o / CCH, c = o - t * CCH;
    size_t gi = base + o;
    io[gi] = io[gi] + hs[t * 97 + c];
  }
}

extern "C" void kernel_launch(void* const* d_in, const int* in_sizes, int n_in,
                              void* d_out, int out_size, void* d_ws, size_t ws_size,
                              hipStream_t stream) {
  const float* x    = (const float*)d_in[0];
  const float* mask = (const float*)d_in[1];
  const float* n1g  = (const float*)d_in[2];
  const float* n1b  = (const float*)d_in[3];
  const float* qkvw = (const float*)d_in[4];
  const float* qkvb = (const float*)d_in[5];
  const float* pw   = (const float*)d_in[6];
  const float* pb   = (const float*)d_in[7];
  const float* n2g  = (const float*)d_in[8];
  const float* n2b  = (const float*)d_in[9];
  const float* w1   = (const float*)d_in[10];
  const float* b1   = (const float*)d_in[11];
  const float* w2   = (const float*)d_in[12];
  const float* b2   = (const float*)d_in[13];
  float* out = (float*)d_out;

  __hip_bfloat16* xw   = (__hip_bfloat16*)d_ws;
  __hip_bfloat16* obuf = xw + (size_t)NTOK * CCH;

  k1_ln_window<<<NTOK / 8, 256, 0, stream>>>(x, n1g, n1b, xw);
  k2_attn<<<dim3(NWIN, HEADS), 256, 0, stream>>>(xw, qkvw, qkvb, mask, obuf);
  k3_proj<<<NWIN, 256, 0, stream>>>(obuf, x, pw, pb, out);
  k4_mlp<<<NTOK / 32, 256, 0, stream>>>(out, n2g, n2b, w1, b1, w2, b2);
}

// Round 2
// 1668.470 us; speedup vs baseline: 1.8967x; 1.8967x over previous
//
#include <hip/hip_runtime.h>
#include <hip/hip_bf16.h>

// Problem constants (B,D,H,W,C) = (2,32,56,56,96); WS=(2,7,7), SS=(1,3,3)
#define NTOK   200704      // B*D*H*W
#define NWIN   2048        // B * 1024 windows
#define NT     98          // tokens per window (2*7*7)
#define CCH    96
#define HEADS  3
#define HD     32
#define HID    384

typedef __attribute__((ext_vector_type(8))) short bf16x8;   // 8 bf16, 4 VGPRs
typedef __attribute__((ext_vector_type(4))) float f32x4;

__device__ __forceinline__ float bf2f(__hip_bfloat16 v) { return __bfloat162float(v); }

// ---------------- Kernel 0: convert MLP weights to bf16 -------------------
__global__ __launch_bounds__(256) void k0_cvt(
    const float* __restrict__ w1, const float* __restrict__ w2,
    __hip_bfloat16* __restrict__ w1b, __hip_bfloat16* __restrict__ w2b) {
  int i = blockIdx.x * 256 + threadIdx.x;
  if (i < HID * CCH) {
    w1b[i] = __float2bfloat16(w1[i]);
    w2b[i] = __float2bfloat16(w2[i]);
  }
}

// ---------------- Kernel 1: LN1 + shift + window partition -> xw (bf16) ----
__global__ __launch_bounds__(256) void k1_ln_window(
    const float* __restrict__ x, const float* __restrict__ g,
    const float* __restrict__ bt, __hip_bfloat16* __restrict__ xw) {
  int token = blockIdx.x * 8 + (threadIdx.x >> 5);
  int lane = threadIdx.x & 31;
  if (token >= NTOK) return;
  int wb = token / NT;
  int n  = token - wb * NT;
  int b = wb >> 10;
  int rem = wb & 1023;
  int wd = rem >> 6, wh = (rem >> 3) & 7, ww = rem & 7;
  int id = n / 49, ih = (n / 7) % 7, iw = n % 7;
  int dd = wd * 2 + id + 1; if (dd >= 32) dd -= 32;
  int hh = wh * 7 + ih + 3; if (hh >= 56) hh -= 56;
  int w2 = ww * 7 + iw + 3; if (w2 >= 56) w2 -= 56;
  const float* src = x + ((((size_t)b * 32 + dd) * 56 + hh) * 56 + w2) * CCH;
  float v0 = src[lane], v1 = src[lane + 32], v2 = src[lane + 64];
  float s = v0 + v1 + v2, ss = v0 * v0 + v1 * v1 + v2 * v2;
  #pragma unroll
  for (int off = 16; off; off >>= 1) {
    s  += __shfl_xor(s,  off, 32);
    ss += __shfl_xor(ss, off, 32);
  }
  float m   = s * (1.f / 96.f);
  float inv = rsqrtf(ss * (1.f / 96.f) - m * m + 1e-5f);
  __hip_bfloat16* dst = xw + (size_t)token * CCH;
  dst[lane]      = __float2bfloat16((v0 - m) * inv * g[lane]      + bt[lane]);
  dst[lane + 32] = __float2bfloat16((v1 - m) * inv * g[lane + 32] + bt[lane + 32]);
  dst[lane + 64] = __float2bfloat16((v2 - m) * inv * g[lane + 64] + bt[lane + 64]);
}

// ---------------- Kernel 2: per (window, head) attention ------------------
__global__ __launch_bounds__(256) void k2_attn(
    const __hip_bfloat16* __restrict__ xw,
    const float* __restrict__ qkv_w, const float* __restrict__ qkv_b,
    const float* __restrict__ mask, __hip_bfloat16* __restrict__ obuf) {
  __shared__ __hip_bfloat16 qs[NT * 34];
  __shared__ __hip_bfloat16 kts[HD * NT];
  __shared__ __hip_bfloat16 vs[NT * 34];
  __shared__ float Bb[NT * NT];   // 9604 floats; first phase holds xw as [98][97]
  int wb = blockIdx.x, h = blockIdx.y, tid = threadIdx.x;

  const __hip_bfloat16* xp = xw + (size_t)wb * (NT * CCH);
  for (int idx = tid; idx < NT * CCH; idx += 256) {
    int n = idx / CCH, c = idx - n * CCH;
    Bb[n * 97 + c] = bf2f(xp[idx]);
  }
  __syncthreads();

  for (int o = tid; o < 3 * 8 * NT; o += 256) {
    int which = o / 784;
    int r = o - which * 784;
    int d4 = r / NT;
    int n = r - d4 * NT;
    int row0 = which * CCH + h * HD + d4 * 4;
    const float* w0 = qkv_w + (size_t)row0 * CCH;
    float a0 = qkv_b[row0], a1 = qkv_b[row0 + 1], a2 = qkv_b[row0 + 2], a3 = qkv_b[row0 + 3];
    const float* xr = &Bb[n * 97];
    #pragma unroll 4
    for (int c = 0; c < CCH; ++c) {
      float xv = xr[c];
      a0 += xv * w0[c];
      a1 += xv * w0[CCH + c];
      a2 += xv * w0[2 * CCH + c];
      a3 += xv * w0[3 * CCH + c];
    }
    int d = d4 * 4;
    if (which == 0) {
      const float sc = 0.17677669529663689f;  // 32^-0.5
      qs[n * 34 + d]     = __float2bfloat16(a0 * sc);
      qs[n * 34 + d + 1] = __float2bfloat16(a1 * sc);
      qs[n * 34 + d + 2] = __float2bfloat16(a2 * sc);
      qs[n * 34 + d + 3] = __float2bfloat16(a3 * sc);
    } else if (which == 1) {
      kts[(d)     * NT + n] = __float2bfloat16(a0);
      kts[(d + 1) * NT + n] = __float2bfloat16(a1);
      kts[(d + 2) * NT + n] = __float2bfloat16(a2);
      kts[(d + 3) * NT + n] = __float2bfloat16(a3);
    } else {
      vs[n * 34 + d]     = __float2bfloat16(a0);
      vs[n * 34 + d + 1] = __float2bfloat16(a1);
      vs[n * 34 + d + 2] = __float2bfloat16(a2);
      vs[n * 34 + d + 3] = __float2bfloat16(a3);
    }
  }
  __syncthreads();

  const float* mrow = mask + (size_t)(wb & 1023) * (NT * NT);
  for (int o = tid; o < 49 * NT; o += 256) {
    int i2 = o / NT, j = o - i2 * NT;
    int i0 = i2 * 2;
    float a0 = 0.f, a1 = 0.f;
    #pragma unroll
    for (int d = 0; d < HD; ++d) {
      float kv = bf2f(kts[d * NT + j]);
      a0 += bf2f(qs[i0 * 34 + d]) * kv;
      a1 += bf2f(qs[(i0 + 1) * 34 + d]) * kv;
    }
    Bb[i0 * NT + j]       = a0 + mrow[i0 * NT + j];
    Bb[(i0 + 1) * NT + j] = a1 + mrow[(i0 + 1) * NT + j];
  }
  __syncthreads();

  if (tid < NT) {
    float* row = &Bb[tid * NT];
    float mx = -1e30f;
    for (int j = 0; j < NT; ++j) mx = fmaxf(mx, row[j]);
    float sum = 0.f;
    for (int j = 0; j < NT; ++j) { float e = __expf(row[j] - mx); row[j] = e; sum += e; }
    float inv = 1.f / sum;
    for (int j = 0; j < NT; ++j) row[j] *= inv;
  }
  __syncthreads();

  __hip_bfloat16* op = obuf + (size_t)wb * (NT * CCH) + h * HD;
  for (int o = tid; o < 49 * HD; o += 256) {
    int i2 = o / HD, d = o - i2 * HD;
    int i0 = 2 * i2;
    float a0 = 0.f, a1 = 0.f;
    for (int j = 0; j < NT; ++j) {
      float vv = bf2f(vs[j * 34 + d]);
      a0 += Bb[i0 * NT + j] * vv;
      a1 += Bb[(i0 + 1) * NT + j] * vv;
    }
    op[(size_t)i0 * CCH + d]       = __float2bfloat16(a0);
    op[(size_t)(i0 + 1) * CCH + d] = __float2bfloat16(a1);
  }
}

// ---------------- Kernel 3: proj + window-reverse + unshift + residual ----
__global__ __launch_bounds__(256) void k3_proj(
    const __hip_bfloat16* __restrict__ obuf, const float* __restrict__ x,
    const float* __restrict__ pw, const float* __restrict__ pb,
    float* __restrict__ out) {
  __shared__ __hip_bfloat16 os[NT * 98];  // stride 98
  __shared__ float outs[NT * 97];
  int wb = blockIdx.x, tid = threadIdx.x;
  const __hip_bfloat16* src = obuf + (size_t)wb * (NT * CCH);
  for (int idx = tid; idx < NT * CCH; idx += 256) {
    int n = idx / CCH, c = idx - n * CCH;
    os[n * 98 + c] = src[idx];
  }
  __syncthreads();
  for (int o = tid; o < 48 * NT; o += 256) {
    int c2 = o / NT, n = o - c2 * NT;
    int c0 = c2 * 2;
    const float* w0 = pw + (size_t)c0 * CCH;
    float a0 = pb[c0], a1 = pb[c0 + 1];
    const __hip_bfloat16* orow = &os[n * 98];
    #pragma unroll 4
    for (int cc = 0; cc < CCH; ++cc) {
      float ov = bf2f(orow[cc]);
      a0 += ov * w0[cc];
      a1 += ov * w0[CCH + cc];
    }
    outs[n * 97 + c0]     = a0;
    outs[n * 97 + c0 + 1] = a1;
  }
  __syncthreads();
  int b = wb >> 10, rem = wb & 1023;
  int wd = rem >> 6, wh = (rem >> 3) & 7, ww = rem & 7;
  for (int o = tid; o < NT * CCH; o += 256) {
    int n = o / CCH, c = o - n * CCH;
    int id = n / 49, ih = (n / 7) % 7, iw = n % 7;
    int dd = wd * 2 + id + 1; if (dd >= 32) dd -= 32;
    int hh = wh * 7 + ih + 3; if (hh >= 56) hh -= 56;
    int w2 = ww * 7 + iw + 3; if (w2 >= 56) w2 -= 56;
    size_t gi = ((((size_t)b * 32 + dd) * 56 + hh) * 56 + w2) * CCH + c;
    out[gi] = x[gi] + outs[n * 97 + c];
  }
}

// ---------------- Kernel 4: MFMA MLP: LN2 + fc1 + GELU + fc2 + residual ---
// 64-token tile per block, 4 waves. mfma_f32_16x16x32_bf16.
// A/B frag: elem j of lane l = M[l&15][(l>>4)*8 + j]; C/D: col=l&15,row=(l>>4)*4+reg.
#define XB_S 104   // Xb row stride (bf16): 52 dwords -> 2-way bank alias (free), 16B aligned
#define H_S  392   // H  row stride (bf16): 196 dwords -> 2-way, 16B aligned
__global__ __launch_bounds__(256, 2) void k4_mlp(
    float* __restrict__ io, const float* __restrict__ g, const float* __restrict__ bt,
    const __hip_bfloat16* __restrict__ w1b, const float* __restrict__ b1,
    const __hip_bfloat16* __restrict__ w2b, const float* __restrict__ b2) {
  __shared__ __hip_bfloat16 Xb[64 * XB_S];   // LN'd tokens (bf16)
  __shared__ __hip_bfloat16 Hs[64 * H_S];    // gelu(fc1) (bf16)
  int tid = threadIdx.x;
  size_t base = (size_t)blockIdx.x * 64 * CCH;

  // ---- LN2 into Xb ----
  {
    int grp = tid >> 5, lane = tid & 31;
    for (int t = grp; t < 64; t += 8) {
      const float* src = io + base + (size_t)t * CCH;
      float v0 = src[lane], v1 = src[lane + 32], v2 = src[lane + 64];
      float s = v0 + v1 + v2, ss = v0 * v0 + v1 * v1 + v2 * v2;
      #pragma unroll
      for (int off = 16; off; off >>= 1) {
        s  += __shfl_xor(s,  off, 32);
        ss += __shfl_xor(ss, off, 32);
      }
      float m   = s * (1.f / 96.f);
      float inv = rsqrtf(ss * (1.f / 96.f) - m * m + 1e-5f);
      Xb[t * XB_S + lane]      = __float2bfloat16((v0 - m) * inv * g[lane]      + bt[lane]);
      Xb[t * XB_S + lane + 32] = __float2bfloat16((v1 - m) * inv * g[lane + 32] + bt[lane + 32]);
      Xb[t * XB_S + lane + 64] = __float2bfloat16((v2 - m) * inv * g[lane + 64] + bt[lane + 64]);
    }
  }
  __syncthreads();

  int wid = tid >> 6;          // wave 0..3
  int lane = tid & 63;
  int lr = lane & 15;          // frag row/col index
  int lq = lane >> 4;          // frag quad

  // ---- fc1: wave wid computes cols [96*wid, 96*wid+96) for all 64 tokens ----
  {
    f32x4 acc[4][6];
    #pragma unroll
    for (int nt = 0; nt < 6; ++nt) {
      float bv = b1[96 * wid + 16 * nt + lr];
      #pragma unroll
      for (int m = 0; m < 4; ++m) acc[m][nt] = {bv, bv, bv, bv};
    }
    #pragma unroll
    for (int ks = 0; ks < 3; ++ks) {
      int k0 = ks * 32;
      bf16x8 a[4];
      #pragma unroll
      for (int m = 0; m < 4; ++m)
        a[m] = *(const bf16x8*)&Xb[(16 * m + lr) * XB_S + k0 + lq * 8];
      #pragma unroll
      for (int nt = 0; nt < 6; ++nt) {
        bf16x8 b = *(const bf16x8*)&w1b[(size_t)(96 * wid + 16 * nt + lr) * CCH + k0 + lq * 8];
        #pragma unroll
        for (int m = 0; m < 4; ++m)
          acc[m][nt] = __builtin_amdgcn_mfma_f32_16x16x32_bf16(a[m], b, acc[m][nt], 0, 0, 0);
      }
    }
    // GELU (exact erf) + store H
    #pragma unroll
    for (int m = 0; m < 4; ++m)
      #pragma unroll
      for (int nt = 0; nt < 6; ++nt)
        #pragma unroll
        for (int r = 0; r < 4; ++r) {
          float v = acc[m][nt][r];
          v = 0.5f * v * (1.f + erff(v * 0.70710678118654752f));
          Hs[(16 * m + lq * 4 + r) * H_S + 96 * wid + 16 * nt + lr] = __float2bfloat16(v);
        }
  }
  __syncthreads();

  // ---- fc2: wave wid computes tokens [16*wid,16*wid+16), all 96 cols ----
  {
    f32x4 acc2[6];
    #pragma unroll
    for (int nt = 0; nt < 6; ++nt) {
      float bv = b2[16 * nt + lr];
      acc2[nt] = {bv, bv, bv, bv};
    }
    for (int k0 = 0; k0 < HID; k0 += 32) {
      bf16x8 a = *(const bf16x8*)&Hs[(16 * wid + lr) * H_S + k0 + lq * 8];
      #pragma unroll
      for (int nt = 0; nt < 6; ++nt) {
        bf16x8 b = *(const bf16x8*)&w2b[(size_t)(16 * nt + lr) * HID + k0 + lq * 8];
        acc2[nt] = __builtin_amdgcn_mfma_f32_16x16x32_bf16(a, b, acc2[nt], 0, 0, 0);
      }
    }
    #pragma unroll
    for (int nt = 0; nt < 6; ++nt)
      #pragma unroll
      for (int r = 0; r < 4; ++r) {
        int t = 16 * wid + lq * 4 + r;
        int c = 16 * nt + lr;
        size_t gi = base + (size_t)t * CCH + c;
        io[gi] = io[gi] + acc2[nt][r];
      }
  }
}

extern "C" void kernel_launch(void* const* d_in, const int* in_sizes, int n_in,
                              void* d_out, int out_size, void* d_ws, size_t ws_size,
                              hipStream_t stream) {
  const float* x    = (const float*)d_in[0];
  const float* mask = (const float*)d_in[1];
  const float* n1g  = (const float*)d_in[2];
  const float* n1b  = (const float*)d_in[3];
  const float* qkvw = (const float*)d_in[4];
  const float* qkvb = (const float*)d_in[5];
  const float* pw   = (const float*)d_in[6];
  const float* pb   = (const float*)d_in[7];
  const float* n2g  = (const float*)d_in[8];
  const float* n2b  = (const float*)d_in[9];
  const float* w1   = (const float*)d_in[10];
  const float* b1   = (const float*)d_in[11];
  const float* w2   = (const float*)d_in[12];
  const float* b2   = (const float*)d_in[13];
  float* out = (float*)d_out;

  __hip_bfloat16* xw   = (__hip_bfloat16*)d_ws;
  __hip_bfloat16* obuf = xw + (size_t)NTOK * CCH;
  __hip_bfloat16* w1b  = obuf + (size_t)NTOK * CCH;
  __hip_bfloat16* w2b  = w1b + HID * CCH;

  k0_cvt<<<(HID * CCH + 255) / 256, 256, 0, stream>>>(w1, w2, w1b, w2b);
  k1_ln_window<<<NTOK / 8, 256, 0, stream>>>(x, n1g, n1b, xw);
  k2_attn<<<dim3(NWIN, HEADS), 256, 0, stream>>>(xw, qkvw, qkvb, mask, obuf);
  k3_proj<<<NWIN, 256, 0, stream>>>(obuf, x, pw, pb, out);
  k4_mlp<<<NTOK / 64, 256, 0, stream>>>(out, n2g, n2b, w1b, b1, w2b, b2);
}